// Round 7
// baseline (3197.732 us; speedup 1.0000x reference)
//
#include <hip/hip_runtime.h>
#include <stdint.h>
#include <math.h>

#define VV 128000
#define DD 2048
#define BB 32
#define SS 8
#define NCAND 4096

// jax_threefry_partitionable 32-bit stream: counter=(0,flat), bits = o0 ^ o1.  (verified R4/R5)

// ---------------- threefry2x32 core (key = (0, 42) from jax.random.key(42)) ----------------
__device__ __forceinline__ uint32_t rotl32(uint32_t x, uint32_t r) {
    return (x << r) | (x >> (32u - r));
}

__device__ __forceinline__ void threefry2x32(uint32_t c0, uint32_t c1,
                                             uint32_t& o0, uint32_t& o1) {
    const uint32_t k0 = 0u, k1 = 42u;
    const uint32_t k2 = 0x1BD11BDAu ^ k0 ^ k1;
    uint32_t x0 = c0 + k0;
    uint32_t x1 = c1 + k1;
    #define TF_ROUND(r) { x0 += x1; x1 = rotl32(x1, r); x1 ^= x0; }
    TF_ROUND(13) TF_ROUND(15) TF_ROUND(26) TF_ROUND(6)
    x0 += k1; x1 += k2 + 1u;
    TF_ROUND(17) TF_ROUND(29) TF_ROUND(16) TF_ROUND(24)
    x0 += k2; x1 += k0 + 2u;
    TF_ROUND(13) TF_ROUND(15) TF_ROUND(26) TF_ROUND(6)
    x0 += k0; x1 += k1 + 3u;
    TF_ROUND(17) TF_ROUND(29) TF_ROUND(16) TF_ROUND(24)
    x0 += k1; x1 += k2 + 4u;
    TF_ROUND(13) TF_ROUND(15) TF_ROUND(26) TF_ROUND(6)
    x0 += k2; x1 += k0 + 5u;
    #undef TF_ROUND
    o0 = x0; o1 = x1;
}

__device__ float gumbel_at(uint32_t flat) {
    uint32_t o0, o1;
    threefry2x32(0u, flat, o0, o1);   // counter (hi=0, lo=flat)
    uint32_t bits = o0 ^ o1;          // partitionable 32-bit path
    uint32_t fb = (bits >> 9) | 0x3F800000u;
    float f = __uint_as_float(fb) - 1.0f;
    const float TINY = 1.17549435e-38f;
    float u = (f > 0.0f) ? f : TINY;
    return -logf(-logf(u));
}

__device__ __forceinline__ uint32_t enc_f32(float f) {
    uint32_t u = __float_as_uint(f);
    return u ^ (0x80000000u | (uint32_t)(((int32_t)u) >> 31));  // order-preserving
}

// ---------------- K1: logits = softcap(hs @ emb^T)/temp ----------------
// Block: 16 v-rows x 32 batches, 4 waves (wave w -> batches w*8..w*8+7).
// Lane: kl = lane&15 (k-split), vl = lane>>4 (v-quad).
// NO LDS staging, NO K-loop barriers: h (256 KB total) is read directly from
// global (wave-broadcast 256B windows, L1/L2-hot); emb streamed with e/en
// software pipeline. waves_per_eu(4,4) pins the VGPR budget at 128:
// acc 32 + e/en 32 + h 32 + addressing ~ 120 -> no spill, 4 waves/SIMD.
// FMA k-order identical to R5 (bit-identical logits/tokens).
__global__ __launch_bounds__(256) __attribute__((amdgpu_waves_per_eu(4, 4)))
void gemv_kernel(
    const float* __restrict__ emb, const float* __restrict__ hidden,
    const int* __restrict__ outpos, const float* __restrict__ temps,
    float* __restrict__ out)
{
    __shared__ float lout[16][33];     // epilogue transpose only

    const int tid   = threadIdx.x;
    const int w     = tid >> 6;        // wave 0..3 -> batch group
    const int lane  = tid & 63;
    const int kl    = lane & 15;       // k-slice lane
    const int vl    = lane >> 4;       // 0..3: v-quad within block
    const int vbase = blockIdx.x * 16;
    const int pos   = outpos[0];
    const int bb0   = w * 8;

    const float* hbase = hidden + (size_t)pos * DD;   // + b*(SS*DD) + k

    float acc[4][8];
    #pragma unroll
    for (int v = 0; v < 4; ++v)
        #pragma unroll
        for (int b = 0; b < 8; ++b) acc[v][b] = 0.0f;

    // emb row pointers for this thread's 4 v-rows
    const float* erow[4];
    #pragma unroll
    for (int v = 0; v < 4; ++v)
        erow[v] = emb + (size_t)(vbase + vl * 4 + v) * DD;

    float4 e[4], en[4];
    #pragma unroll
    for (int v = 0; v < 4; ++v)
        e[v] = *reinterpret_cast<const float4*>(erow[v] + kl * 4);

    #pragma unroll 4
    for (int qq = 0; qq < DD / 64; ++qq) {
        const int ko = qq * 64 + kl * 4;
        if (qq < DD / 64 - 1) {
            #pragma unroll
            for (int v = 0; v < 4; ++v)
                en[v] = *reinterpret_cast<const float4*>(erow[v] + ko + 64);
        }
        float4 h[8];
        #pragma unroll
        for (int b = 0; b < 8; ++b)
            h[b] = *reinterpret_cast<const float4*>(
                hbase + (size_t)(bb0 + b) * (SS * DD) + ko);
        #pragma unroll
        for (int b = 0; b < 8; ++b) {
            #pragma unroll
            for (int v = 0; v < 4; ++v) {
                acc[v][b] += e[v].x * h[b].x;
                acc[v][b] += e[v].y * h[b].y;
                acc[v][b] += e[v].z * h[b].z;
                acc[v][b] += e[v].w * h[b].w;
            }
        }
        #pragma unroll
        for (int v = 0; v < 4; ++v) e[v] = en[v];
    }

    // reduce partial dots across the 16 k-lanes (identical to R5)
    #pragma unroll
    for (int v = 0; v < 4; ++v)
        #pragma unroll
        for (int b = 0; b < 8; ++b) {
            float a = acc[v][b];
            a += __shfl_xor(a, 1, 64);
            a += __shfl_xor(a, 2, 64);
            a += __shfl_xor(a, 4, 64);
            a += __shfl_xor(a, 8, 64);
            acc[v][b] = a;
        }

    if (kl == 0) {
        #pragma unroll
        for (int v = 0; v < 4; ++v)
            #pragma unroll
            for (int b = 0; b < 8; ++b) {
                float raw = acc[v][b];
                float l = tanhf(raw / 30.0f) * 30.0f;   // final logit softcapping
                l = l / temps[bb0 + b];                  // temperature
                lout[vl * 4 + v][bb0 + b] = l;
            }
    }
    __syncthreads();
    #pragma unroll
    for (int r = 0; r < 2; ++r) {
        int idx = tid + r * 256;
        int b2  = idx >> 4;
        int vv2 = idx & 15;
        out[32 + (size_t)b2 * VV + vbase + vv2] = lout[vv2][b2];
    }
}

// ---------------- K2: per-row top-64 (prob-sorted, stable) + exact-RNG categorical ----------------
__global__ __launch_bounds__(1024) void sample_kernel(
    float* __restrict__ dout, const float* __restrict__ top_ps,
    const int* __restrict__ top_ks)
{
    const int b   = blockIdx.x;
    const int tid = threadIdx.x;
    const float* row = dout + 32 + (size_t)b * VV;

    __shared__ unsigned int hist[2048];            // 8KB
    __shared__ unsigned long long arr[NCAND];      // 32KB: (enc(p)<<32)|~idx
    __shared__ float red[1024];                    // 4KB
    __shared__ float m_sh;
    __shared__ unsigned int thresh_sh;
    __shared__ unsigned int cnt_sh;
    __shared__ float p_arr[64];
    __shared__ unsigned int idx_arr[64];
    __shared__ float S_sh;
    __shared__ unsigned long long keep_sh;

    for (int i = tid; i < 2048; i += 1024) hist[i] = 0u;
    for (int i = tid; i < NCAND; i += 1024) arr[i] = 0ull;
    if (tid == 0) cnt_sh = 0u;
    __syncthreads();

    // ---- pass A: row max + 11-bit float-order histogram ----
    float lmax = -INFINITY;
    for (int i = tid; i < VV; i += 1024) {
        float l = row[i];
        lmax = fmaxf(lmax, l);
        atomicAdd(&hist[enc_f32(l) >> 21], 1u);
    }
    red[tid] = lmax;
    __syncthreads();
    for (int s = 512; s > 0; s >>= 1) {
        if (tid < s) red[tid] = fmaxf(red[tid], red[tid + s]);
        __syncthreads();
    }
    if (tid == 0) {
        float m = red[0];
        m_sh = m;
        int t = (int)(enc_f32(m) >> 21);
        unsigned int cum = 0u;
        for (; t >= 0; --t) { cum += hist[t]; if (cum >= 64u) break; }
        if (t < 0) t = 0;
        thresh_sh = ((unsigned int)t) << 21;
    }
    __syncthreads();
    const float m = m_sh;
    const unsigned int thresh = thresh_sh;

    // ---- pass B: softmax denominator Z ----
    float z = 0.0f;
    for (int i = tid; i < VV; i += 1024) z += expf(row[i] - m);
    red[tid] = z;
    __syncthreads();
    for (int s = 512; s > 0; s >>= 1) {
        if (tid < s) red[tid] += red[tid + s];
        __syncthreads();
    }
    const float Z = red[0];
    __syncthreads();

    // ---- pass C: collect candidates keyed by (prob desc, idx asc) ----
    for (int i = tid; i < VV; i += 1024) {
        float l = row[i];
        if (enc_f32(l) >= thresh) {
            float p = expf(l - m) / Z;
            unsigned int slot = atomicAdd(&cnt_sh, 1u);
            if (slot < NCAND)
                arr[slot] = ((unsigned long long)enc_f32(p) << 32)
                          | (unsigned long long)(~(unsigned int)i);
        }
    }
    __syncthreads();

    // ---- bitonic sort, descending (zeros sink to the end) ----
    for (int k = 2; k <= NCAND; k <<= 1) {
        for (int j = k >> 1; j > 0; j >>= 1) {
            for (int t = tid; t < NCAND; t += 1024) {
                int ixj = t ^ j;
                if (ixj > t) {
                    unsigned long long a = arr[t], c = arr[ixj];
                    bool desc = ((t & k) == 0);
                    if (desc ? (a < c) : (a > c)) { arr[t] = c; arr[ixj] = a; }
                }
            }
            __syncthreads();
        }
    }

    // ---- decode top-64 ----
    if (tid < 64) {
        unsigned long long key = arr[tid];
        p_arr[tid]   = __uint_as_float((unsigned int)(key >> 32) & 0x7FFFFFFFu);
        idx_arr[tid] = ~((unsigned int)(key & 0xFFFFFFFFull));
    }
    __syncthreads();

    // ---- sequential fp32 cumsum + top-p/top-k keep mask (np order) ----
    if (tid == 0) {
        float cum = 0.0f, S = 0.0f;
        unsigned long long keep = 0ull;
        const float tp = top_ps[b];
        const int   tk = top_ks[b];
        for (int r = 0; r < 64; ++r) {
            float p = p_arr[r];
            cum = cum + p;
            float excl = cum - p;
            if (!(excl > tp) && (r < tk)) { keep |= (1ull << r); S = S + p; }
        }
        S_sh = S; keep_sh = keep;
    }
    __syncthreads();

    // ---- gumbel-max over kept set (exact jax.random.categorical(key(42))) ----
    if (tid < 64) {
        unsigned long long pk = 0ull;
        if ((keep_sh >> tid) & 1ull) {
            float q  = p_arr[tid] / S_sh;
            float lp = logf(q);
            unsigned int idx = idx_arr[tid];
            float g = gumbel_at((unsigned int)b * (unsigned int)VV + idx);
            float vf = lp + g;
            pk = ((unsigned long long)enc_f32(vf) << 32)
               | (unsigned long long)(~idx);
        }
        for (int off = 1; off < 64; off <<= 1) {
            unsigned long long o = __shfl_xor(pk, off, 64);
            if (o > pk) pk = o;
        }
        if (tid == 0) {
            unsigned int token = ~((unsigned int)(pk & 0xFFFFFFFFull));
            dout[b] = (float)token;
        }
    }
}

extern "C" void kernel_launch(void* const* d_in, const int* in_sizes, int n_in,
                              void* d_out, int out_size, void* d_ws, size_t ws_size,
                              hipStream_t stream) {
    const float* emb   = (const float*)d_in[0];
    const float* hid   = (const float*)d_in[1];
    const int*   pos   = (const int*)d_in[2];
    const float* temps = (const float*)d_in[3];
    const float* tps   = (const float*)d_in[4];
    const int*   tks   = (const int*)d_in[5];
    float* out = (float*)d_out;

    gemv_kernel<<<dim3(VV / 16), dim3(256), 0, stream>>>(emb, hid, pos, temps, out);
    sample_kernel<<<dim3(BB), dim3(1024), 0, stream>>>(out, tps, tks);
}

// Round 8
// 621.512 us; speedup vs baseline: 5.1451x; 5.1451x over previous
//
#include <hip/hip_runtime.h>
#include <stdint.h>
#include <math.h>

#define VV 128000
#define DD 2048
#define BB 32
#define SS 8
#define CH 64          // floats per K-chunk
#define NCH (DD / CH)  // 32 chunks
#define NCAND 4096

// jax_threefry_partitionable 32-bit stream: counter=(0,flat), bits = o0 ^ o1.  (verified R4/R5)

// direct global->LDS (no VGPR round-trip); dest = wave-uniform base + lane*16
#define GLDS(src, dst) __builtin_amdgcn_global_load_lds( \
    (const __attribute__((address_space(1))) void*)(src), \
    (__attribute__((address_space(3))) void*)(dst), 16, 0, 0)

// ---------------- threefry2x32 core (key = (0, 42) from jax.random.key(42)) ----------------
__device__ __forceinline__ uint32_t rotl32(uint32_t x, uint32_t r) {
    return (x << r) | (x >> (32u - r));
}

__device__ __forceinline__ void threefry2x32(uint32_t c0, uint32_t c1,
                                             uint32_t& o0, uint32_t& o1) {
    const uint32_t k0 = 0u, k1 = 42u;
    const uint32_t k2 = 0x1BD11BDAu ^ k0 ^ k1;
    uint32_t x0 = c0 + k0;
    uint32_t x1 = c1 + k1;
    #define TF_ROUND(r) { x0 += x1; x1 = rotl32(x1, r); x1 ^= x0; }
    TF_ROUND(13) TF_ROUND(15) TF_ROUND(26) TF_ROUND(6)
    x0 += k1; x1 += k2 + 1u;
    TF_ROUND(17) TF_ROUND(29) TF_ROUND(16) TF_ROUND(24)
    x0 += k2; x1 += k0 + 2u;
    TF_ROUND(13) TF_ROUND(15) TF_ROUND(26) TF_ROUND(6)
    x0 += k0; x1 += k1 + 3u;
    TF_ROUND(17) TF_ROUND(29) TF_ROUND(16) TF_ROUND(24)
    x0 += k1; x1 += k2 + 4u;
    TF_ROUND(13) TF_ROUND(15) TF_ROUND(26) TF_ROUND(6)
    x0 += k2; x1 += k0 + 5u;
    #undef TF_ROUND
    o0 = x0; o1 = x1;
}

__device__ float gumbel_at(uint32_t flat) {
    uint32_t o0, o1;
    threefry2x32(0u, flat, o0, o1);   // counter (hi=0, lo=flat)
    uint32_t bits = o0 ^ o1;          // partitionable 32-bit path
    uint32_t fb = (bits >> 9) | 0x3F800000u;
    float f = __uint_as_float(fb) - 1.0f;
    const float TINY = 1.17549435e-38f;
    float u = (f > 0.0f) ? f : TINY;
    return -logf(-logf(u));
}

__device__ __forceinline__ uint32_t enc_f32(float f) {
    uint32_t u = __float_as_uint(f);
    return u ^ (0x80000000u | (uint32_t)(((int32_t)u) >> 31));  // order-preserving
}

// ---------------- K1: logits = softcap(hs @ emb^T)/temp ----------------
// Block: 512 threads = 8 waves; 16 v-rows x 32 batches per block.
// Wave w owns batches w*4..w*4+3 (stages ITS OWN hidden rows -> wave-private
// pipeline, NO __syncthreads in the K-loop). Lane: kl=lane&15 k-split,
// vl=lane>>4 v-quad. Per-thread tile acc[4v][4b]=16 + e[4]=16 + h[4]=16 regs.
// hs ring: 3 buffers, staged 2 ahead via global_load_lds; s_waitcnt vmcnt(6)
// before ds_reads (6 = S(c+1) + 4 e-loads + S(c+2) younger ops outstanding).
// FMA k-order per acc element identical to R5 (bit-identical logits/tokens).
__global__ __launch_bounds__(512, 4) void gemv_kernel(
    const float* __restrict__ emb, const float* __restrict__ hidden,
    const int* __restrict__ outpos, const float* __restrict__ temps,
    float* __restrict__ out)
{
    __shared__ float hs[3][BB][CH];    // 24 KB ring
    __shared__ float lout[16][33];     // epilogue transpose

    const int tid   = threadIdx.x;
    const int w     = tid >> 6;        // wave 0..7
    const int lane  = tid & 63;
    const int kl    = lane & 15;
    const int vl    = lane >> 4;       // 0..3
    const int vbase = blockIdx.x * 16;
    const int pos   = outpos[0];
    const int bb0   = w << 2;          // this wave's 4 batches

    const float* hbase = hidden + (size_t)pos * DD;
    // per-lane stage source: batch row bb0 + (lane>>4), col (lane&15)*4
    const float* gstage = hbase + (size_t)(bb0 + (lane >> 4)) * (SS * DD) + (kl << 2);

    float acc[4][4];
    #pragma unroll
    for (int v = 0; v < 4; ++v)
        #pragma unroll
        for (int b = 0; b < 4; ++b) acc[v][b] = 0.0f;

    // prologue: stage chunks 0 and 1 (wave-private)
    GLDS(gstage,      &hs[0][bb0][0]);
    GLDS(gstage + CH, &hs[1][bb0][0]);
    const float* gst = gstage + 2 * CH;

    int rb = 0, wb = 2;
    for (int c = 0; c < NCH; ++c) {
        // e-loads first (so their wait never gates on fresh staging)
        float4 e0 = *reinterpret_cast<const float4*>(
            emb + (size_t)(vbase + (vl << 2) + 0) * DD + c * CH + (kl << 2));
        float4 e1 = *reinterpret_cast<const float4*>(
            emb + (size_t)(vbase + (vl << 2) + 1) * DD + c * CH + (kl << 2));
        float4 e2 = *reinterpret_cast<const float4*>(
            emb + (size_t)(vbase + (vl << 2) + 2) * DD + c * CH + (kl << 2));
        float4 e3 = *reinterpret_cast<const float4*>(
            emb + (size_t)(vbase + (vl << 2) + 3) * DD + c * CH + (kl << 2));
        // stage chunk c+2 into ring slot wb
        if (c < NCH - 2) {
            GLDS(gst, &hs[wb][bb0][0]);
            gst += CH;
        }
        // ensure chunk c staged (<=6 younger vmem ops may remain in flight)
        asm volatile("s_waitcnt vmcnt(6)" ::: "memory");
        const float4 h0 = *reinterpret_cast<const float4*>(&hs[rb][bb0 + 0][kl << 2]);
        const float4 h1 = *reinterpret_cast<const float4*>(&hs[rb][bb0 + 1][kl << 2]);
        const float4 h2 = *reinterpret_cast<const float4*>(&hs[rb][bb0 + 2][kl << 2]);
        const float4 h3 = *reinterpret_cast<const float4*>(&hs[rb][bb0 + 3][kl << 2]);
        #define FMA4(V, EV) \
            acc[V][0] += EV.x * h0.x; acc[V][0] += EV.y * h0.y; \
            acc[V][0] += EV.z * h0.z; acc[V][0] += EV.w * h0.w; \
            acc[V][1] += EV.x * h1.x; acc[V][1] += EV.y * h1.y; \
            acc[V][1] += EV.z * h1.z; acc[V][1] += EV.w * h1.w; \
            acc[V][2] += EV.x * h2.x; acc[V][2] += EV.y * h2.y; \
            acc[V][2] += EV.z * h2.z; acc[V][2] += EV.w * h2.w; \
            acc[V][3] += EV.x * h3.x; acc[V][3] += EV.y * h3.y; \
            acc[V][3] += EV.z * h3.z; acc[V][3] += EV.w * h3.w;
        FMA4(0, e0) FMA4(1, e1) FMA4(2, e2) FMA4(3, e3)
        #undef FMA4
        rb = (rb == 2) ? 0 : rb + 1;
        wb = (wb == 2) ? 0 : wb + 1;
    }

    // reduce partial dots across the 16 k-lanes (identical tree to R5)
    #pragma unroll
    for (int v = 0; v < 4; ++v)
        #pragma unroll
        for (int b = 0; b < 4; ++b) {
            float a = acc[v][b];
            a += __shfl_xor(a, 1, 64);
            a += __shfl_xor(a, 2, 64);
            a += __shfl_xor(a, 4, 64);
            a += __shfl_xor(a, 8, 64);
            acc[v][b] = a;
        }

    if (kl == 0) {
        #pragma unroll
        for (int v = 0; v < 4; ++v)
            #pragma unroll
            for (int b = 0; b < 4; ++b) {
                float raw = acc[v][b];
                float l = tanhf(raw / 30.0f) * 30.0f;   // final logit softcapping
                l = l / temps[bb0 + b];                  // temperature
                lout[(vl << 2) + v][bb0 + b] = l;
            }
    }
    __syncthreads();
    // coalesced store: 512 logits, one per thread
    {
        int b2  = tid >> 4;
        int vv2 = tid & 15;
        out[32 + (size_t)b2 * VV + vbase + vv2] = lout[vv2][b2];
    }
}

// ---------------- K2: per-row top-64 (prob-sorted, stable) + exact-RNG categorical ----------------
__global__ __launch_bounds__(1024) void sample_kernel(
    float* __restrict__ dout, const float* __restrict__ top_ps,
    const int* __restrict__ top_ks)
{
    const int b   = blockIdx.x;
    const int tid = threadIdx.x;
    const float* row = dout + 32 + (size_t)b * VV;

    __shared__ unsigned int hist[2048];            // 8KB
    __shared__ unsigned long long arr[NCAND];      // 32KB: (enc(p)<<32)|~idx
    __shared__ float red[1024];                    // 4KB
    __shared__ float m_sh;
    __shared__ unsigned int thresh_sh;
    __shared__ unsigned int cnt_sh;
    __shared__ float p_arr[64];
    __shared__ unsigned int idx_arr[64];
    __shared__ float S_sh;
    __shared__ unsigned long long keep_sh;

    for (int i = tid; i < 2048; i += 1024) hist[i] = 0u;
    for (int i = tid; i < NCAND; i += 1024) arr[i] = 0ull;
    if (tid == 0) cnt_sh = 0u;
    __syncthreads();

    // ---- pass A: row max + 11-bit float-order histogram ----
    float lmax = -INFINITY;
    for (int i = tid; i < VV; i += 1024) {
        float l = row[i];
        lmax = fmaxf(lmax, l);
        atomicAdd(&hist[enc_f32(l) >> 21], 1u);
    }
    red[tid] = lmax;
    __syncthreads();
    for (int s = 512; s > 0; s >>= 1) {
        if (tid < s) red[tid] = fmaxf(red[tid], red[tid + s]);
        __syncthreads();
    }
    if (tid == 0) {
        float m = red[0];
        m_sh = m;
        int t = (int)(enc_f32(m) >> 21);
        unsigned int cum = 0u;
        for (; t >= 0; --t) { cum += hist[t]; if (cum >= 64u) break; }
        if (t < 0) t = 0;
        thresh_sh = ((unsigned int)t) << 21;
    }
    __syncthreads();
    const float m = m_sh;
    const unsigned int thresh = thresh_sh;

    // ---- pass B: softmax denominator Z ----
    float z = 0.0f;
    for (int i = tid; i < VV; i += 1024) z += expf(row[i] - m);
    red[tid] = z;
    __syncthreads();
    for (int s = 512; s > 0; s >>= 1) {
        if (tid < s) red[tid] += red[tid + s];
        __syncthreads();
    }
    const float Z = red[0];
    __syncthreads();

    // ---- pass C: collect candidates keyed by (prob desc, idx asc) ----
    for (int i = tid; i < VV; i += 1024) {
        float l = row[i];
        if (enc_f32(l) >= thresh) {
            float p = expf(l - m) / Z;
            unsigned int slot = atomicAdd(&cnt_sh, 1u);
            if (slot < NCAND)
                arr[slot] = ((unsigned long long)enc_f32(p) << 32)
                          | (unsigned long long)(~(unsigned int)i);
        }
    }
    __syncthreads();

    // ---- bitonic sort, descending (zeros sink to the end) ----
    for (int k = 2; k <= NCAND; k <<= 1) {
        for (int j = k >> 1; j > 0; j >>= 1) {
            for (int t = tid; t < NCAND; t += 1024) {
                int ixj = t ^ j;
                if (ixj > t) {
                    unsigned long long a = arr[t], c = arr[ixj];
                    bool desc = ((t & k) == 0);
                    if (desc ? (a < c) : (a > c)) { arr[t] = c; arr[ixj] = a; }
                }
            }
            __syncthreads();
        }
    }

    // ---- decode top-64 ----
    if (tid < 64) {
        unsigned long long key = arr[tid];
        p_arr[tid]   = __uint_as_float((unsigned int)(key >> 32) & 0x7FFFFFFFu);
        idx_arr[tid] = ~((unsigned int)(key & 0xFFFFFFFFull));
    }
    __syncthreads();

    // ---- sequential fp32 cumsum + top-p/top-k keep mask (np order) ----
    if (tid == 0) {
        float cum = 0.0f, S = 0.0f;
        unsigned long long keep = 0ull;
        const float tp = top_ps[b];
        const int   tk = top_ks[b];
        for (int r = 0; r < 64; ++r) {
            float p = p_arr[r];
            cum = cum + p;
            float excl = cum - p;
            if (!(excl > tp) && (r < tk)) { keep |= (1ull << r); S = S + p; }
        }
        S_sh = S; keep_sh = keep;
    }
    __syncthreads();

    // ---- gumbel-max over kept set (exact jax.random.categorical(key(42))) ----
    if (tid < 64) {
        unsigned long long pk = 0ull;
        if ((keep_sh >> tid) & 1ull) {
            float q  = p_arr[tid] / S_sh;
            float lp = logf(q);
            unsigned int idx = idx_arr[tid];
            float g = gumbel_at((unsigned int)b * (unsigned int)VV + idx);
            float vf = lp + g;
            pk = ((unsigned long long)enc_f32(vf) << 32)
               | (unsigned long long)(~idx);
        }
        for (int off = 1; off < 64; off <<= 1) {
            unsigned long long o = __shfl_xor(pk, off, 64);
            if (o > pk) pk = o;
        }
        if (tid == 0) {
            unsigned int token = ~((unsigned int)(pk & 0xFFFFFFFFull));
            dout[b] = (float)token;
        }
    }
}

extern "C" void kernel_launch(void* const* d_in, const int* in_sizes, int n_in,
                              void* d_out, int out_size, void* d_ws, size_t ws_size,
                              hipStream_t stream) {
    const float* emb   = (const float*)d_in[0];
    const float* hid   = (const float*)d_in[1];
    const int*   pos   = (const int*)d_in[2];
    const float* temps = (const float*)d_in[3];
    const float* tps   = (const float*)d_in[4];
    const int*   tks   = (const int*)d_in[5];
    float* out = (float*)d_out;

    gemv_kernel<<<dim3(VV / 16), dim3(512), 0, stream>>>(emb, hid, pos, temps, out);
    sample_kernel<<<dim3(BB), dim3(1024), 0, stream>>>(out, tps, tks);
}